// Round 15
// baseline (465.660 us; speedup 1.0000x reference)
//
#include <hip/hip_runtime.h>
#include <hip/hip_bf16.h>

typedef __bf16    bf16x8_t __attribute__((ext_vector_type(8)));
typedef float     f32x4_t  __attribute__((ext_vector_type(4)));
typedef short     s16x4_t  __attribute__((ext_vector_type(4)));
typedef short     s16x8_t  __attribute__((ext_vector_type(8)));
typedef unsigned  u32x4_t  __attribute__((ext_vector_type(4)));

#define S_LEN 2048
#define HDIM  64
#define BQ    32
#define NTHREADS 512
#define PSTR_B 4112       // P row byte stride; %128B=16 -> rows shift 4 banks
#define BMSTR 264

__device__ __forceinline__ short f2bf(float f) {
    return __builtin_bit_cast(short, (__bf16)f);
}
__device__ __forceinline__ float bf2f(short s) {
    return __builtin_bit_cast(float, ((unsigned)(unsigned short)s) << 16);
}
__device__ __forceinline__ short* pelem(short* P, int row, int e) {
    return (short*)((char*)P + (unsigned)row * PSTR_B + (unsigned)e * 2u);
}
__device__ __forceinline__ const short* pelemc(const short* P, int row, int e) {
    return pelem(const_cast<short*>(P), row, e);
}
__device__ __forceinline__ unsigned nzmask16(u32x4_t w) {
    unsigned n = 0;
    #pragma unroll
    for (int i = 0; i < 4; ++i) {
        const unsigned x = w[i];
        const unsigned t = (x & 0x7F7F7F7Fu) + 0x7F7F7F7Fu;
        const unsigned z = ((t | x) & 0x80808080u) >> 7;
        n |= ((z * 0x10204081u) >> 28) << (4 * i);
    }
    return n;
}
__device__ __forceinline__ unsigned nzmask4w(u32x4_t w) {
    return (w[0] ? 1u : 0u) | (w[1] ? 2u : 0u) | (w[2] ? 4u : 0u) | (w[3] ? 8u : 0u);
}

#define PK8(lo, hi, out8) { s16x8_t _t; \
    _t[0]=f2bf((lo)[0]); _t[1]=f2bf((lo)[1]); _t[2]=f2bf((lo)[2]); _t[3]=f2bf((lo)[3]); \
    _t[4]=f2bf((hi)[0]); _t[5]=f2bf((hi)[1]); _t[6]=f2bf((hi)[2]); _t[7]=f2bf((hi)[3]); \
    (out8) = __builtin_bit_cast(bf16x8_t, _t); }
#define PKV(src, dst) { s16x8_t _t; \
    _t[0]=f2bf((src)[0]); _t[1]=f2bf((src)[1]); _t[2]=f2bf((src)[2]); _t[3]=f2bf((src)[3]); \
    _t[4]=f2bf((src)[4]); _t[5]=f2bf((src)[5]); _t[6]=f2bf((src)[6]); _t[7]=f2bf((src)[7]); \
    (dst) = __builtin_bit_cast(bf16x8_t, _t); }

__global__ void detect_mask(const unsigned char* __restrict__ M, int* __restrict__ flags) {
    __shared__ int cnt[4];
    if (threadIdx.x < 4) cnt[threadIdx.x] = 0;
    __syncthreads();
    int local[4] = {0, 0, 0, 0};
    for (int i = threadIdx.x; i < 16384; i += 256)
        if (M[i]) local[i & 3]++;
    #pragma unroll
    for (int c = 0; c < 4; ++c)
        if (local[c]) atomicAdd(&cnt[c], local[c]);
    __syncthreads();
    if (threadIdx.x == 0) {
        int stride;
        if (cnt[1] == 0 && cnt[2] == 0 && cnt[3] == 0)      stride = 4;  // int32
        else if (cnt[0] == 0 && cnt[1] == 0)                stride = 4;  // float32
        else                                                stride = 1;  // bool/int8
        flags[0] = stride;
    }
}

// r14 structure with ALL hot loops ROLLED (#pragma unroll 1): hot code ~4KB,
// fully L1I-resident. Single-variable test of the instruction-cache theory
// (everything-idle stalls that no data-path fix moved in r9/r13/r14).
__global__ __launch_bounds__(NTHREADS, 2)
void sdpa_one(const float* __restrict__ Q, const float* __restrict__ K,
              const float* __restrict__ V, const unsigned char* __restrict__ M,
              const int* __restrict__ MF, float* __restrict__ OUT)
{
    __shared__ short Plds[BQ * (PSTR_B / 2)];      // 131584 B unnormalized exp bf16
    __shared__ unsigned char Bm[BQ * BMSTR];       // 8448 B mask bits
    __shared__ float Pvp[4][BQ][17];               // PV k-half partials
    __shared__ float rowsum[BQ];
    __shared__ float rinv_s[BQ];

    const int tid  = threadIdx.x;
    const int w    = tid >> 6;
    const int lane = tid & 63;
    const int col  = lane & 15;
    const int kg   = lane >> 4;
    const int mstride = MF[0];

    // 2048 blocks = 8 xcd * 256 slots (bijective)
    const int id   = blockIdx.x;
    const int slot = id >> 3;
    const int b    = ((slot >> 6) << 3) | (id & 7);
    const int q0   = (slot & 63) * BQ;

    float* attn_out = OUT + (size_t)32 * S_LEN * HDIM;

    if (tid < BQ) rowsum[tid] = 0.f;

    {   // ---- mask tile -> 1-bit/elem LDS bitmask (rolled)
        const int row  = tid >> 4;
        const int segE = (tid & 15) * 128;
        unsigned long long bits[2] = {0ull, 0ull};
        if (mstride == 1) {
            const unsigned char* mp = M + (size_t)b * S_LEN * S_LEN
                                        + (size_t)(q0 + row) * S_LEN + segE;
            #pragma unroll 1
            for (int j = 0; j < 8; ++j)
                bits[j >> 2] |= (unsigned long long)nzmask16(*(const u32x4_t*)(mp + j * 16))
                                << (16 * (j & 3));
        } else {
            const unsigned* mp = (const unsigned*)M + (size_t)b * S_LEN * S_LEN
                                   + (size_t)(q0 + row) * S_LEN + segE;
            #pragma unroll 1
            for (int j = 0; j < 32; ++j)
                bits[j >> 4] |= (unsigned long long)nzmask4w(*(const u32x4_t*)(mp + j * 4))
                                << (4 * (j & 15));
        }
        unsigned long long* bp = (unsigned long long*)&Bm[row * BMSTR + (tid & 15) * 16];
        bp[0] = bits[0]; bp[1] = bits[1];
    }

    // Q fragments (MFMA B-operand after swap; same lane layout)
    bf16x8_t af[2][2];
    #pragma unroll
    for (int m = 0; m < 2; ++m)
        #pragma unroll
        for (int kk = 0; kk < 2; ++kk) {
            const float* qp = Q + ((size_t)b * S_LEN + q0 + m * 16 + col) * HDIM + kk * 32 + kg * 8;
            const f32x4_t qa = *(const f32x4_t*)qp;
            const f32x4_t qb = *(const f32x4_t*)(qp + 4);
            PK8(qa, qb, af[m][kk]);
        }
    __syncthreads();

    // ---- Phase 1 (ROLLED): swapped QK^T. D = mfma(A=K_frag, B=Q_frag):
    // lane(col,kg) reg r -> P[q=m*16+col][k = n0 + kg*4 + r].
    float rs0 = 0.f, rs1 = 0.f;
    {
        const float* Kb = K + (size_t)b * S_LEN * HDIM;
        f32x4_t A0,B0,C0,D0, A1,B1,C1,D1;
#define LDK(f, AX,BX,CX,DX) { \
    const float* kp = Kb + (size_t)(w * 256 + (f) * 16 + col) * HDIM + kg * 8; \
    AX = *(const f32x4_t*)kp;        BX = *(const f32x4_t*)(kp + 4); \
    CX = *(const f32x4_t*)(kp + 32); DX = *(const f32x4_t*)(kp + 36); }
#define STEP(f, AX,BX,CX,DX, PF, fp) { \
    bf16x8_t kb0, kb1; PK8(AX, BX, kb0); PK8(CX, DX, kb1); \
    if (PF) LDK(fp, AX,BX,CX,DX); \
    f32x4_t acc0 = {0.f,0.f,0.f,0.f}, acc1 = {0.f,0.f,0.f,0.f}; \
    acc0 = __builtin_amdgcn_mfma_f32_16x16x32_bf16(kb0, af[0][0], acc0, 0,0,0); \
    acc0 = __builtin_amdgcn_mfma_f32_16x16x32_bf16(kb1, af[0][1], acc0, 0,0,0); \
    acc1 = __builtin_amdgcn_mfma_f32_16x16x32_bf16(kb0, af[1][0], acc1, 0,0,0); \
    acc1 = __builtin_amdgcn_mfma_f32_16x16x32_bf16(kb1, af[1][1], acc1, 0,0,0); \
    const int c0 = w * 256 + (f) * 16 + kg * 4; \
    const int sh = c0 & 7; \
    { const unsigned bb = Bm[col * BMSTR + (c0 >> 3)]; \
      float p0 = ((bb >> (sh    )) & 1u) ? 0.f : __expf(acc0[0] * 0.125f); \
      float p1 = ((bb >> (sh + 1)) & 1u) ? 0.f : __expf(acc0[1] * 0.125f); \
      float p2 = ((bb >> (sh + 2)) & 1u) ? 0.f : __expf(acc0[2] * 0.125f); \
      float p3 = ((bb >> (sh + 3)) & 1u) ? 0.f : __expf(acc0[3] * 0.125f); \
      rs0 += (p0 + p1) + (p2 + p3); \
      s16x4_t pk; pk[0]=f2bf(p0); pk[1]=f2bf(p1); pk[2]=f2bf(p2); pk[3]=f2bf(p3); \
      *(s16x4_t*)pelem(Plds, col, c0) = pk; } \
    { const unsigned bb = Bm[(16 + col) * BMSTR + (c0 >> 3)]; \
      float p0 = ((bb >> (sh    )) & 1u) ? 0.f : __expf(acc1[0] * 0.125f); \
      float p1 = ((bb >> (sh + 1)) & 1u) ? 0.f : __expf(acc1[1] * 0.125f); \
      float p2 = ((bb >> (sh + 2)) & 1u) ? 0.f : __expf(acc1[2] * 0.125f); \
      float p3 = ((bb >> (sh + 3)) & 1u) ? 0.f : __expf(acc1[3] * 0.125f); \
      rs1 += (p0 + p1) + (p2 + p3); \
      s16x4_t pk; pk[0]=f2bf(p0); pk[1]=f2bf(p1); pk[2]=f2bf(p2); pk[3]=f2bf(p3); \
      *(s16x4_t*)pelem(Plds, 16 + col, c0) = pk; } }
        LDK(0, A0,B0,C0,D0);
        LDK(1, A1,B1,C1,D1);
        #pragma unroll 1
        for (int ff = 0; ff < 16; ff += 2) {
            STEP(ff,     A0,B0,C0,D0, (ff + 2 < 16), ff + 2);
            STEP(ff + 1, A1,B1,C1,D1, (ff + 3 < 16), ff + 3);
        }
#undef LDK
#undef STEP
    }
    {
        float s0 = rs0, s1 = rs1;
        s0 += __shfl_xor(s0, 16); s0 += __shfl_xor(s0, 32);
        s1 += __shfl_xor(s1, 16); s1 += __shfl_xor(s1, 32);
        if (lane < 16) {
            atomicAdd(&rowsum[col], s0);
            atomicAdd(&rowsum[16 + col], s1);
        }
    }
    __syncthreads();
    if (tid < BQ) rinv_s[tid] = 1.0f / rowsum[tid];
    __syncthreads();

    // ---- Phase 2a (ROLLED): pure PV, depth-2 V rotation
    const int hb    = (w & 3) * 16;
    const int kbase = (w >> 2) * 1024;
    const float* Vb = V + (size_t)b * S_LEN * HDIM;

    f32x4_t cacc0 = {0.f,0.f,0.f,0.f}, cacc1 = {0.f,0.f,0.f,0.f};
    {
        float vr0[8], vr1[8];
#define LOADV(kc, dst) { \
    const float* vp = Vb + (size_t)(kbase + (kc) * 32 + kg * 8) * HDIM + hb + col; \
    dst[0] = vp[0];        dst[1] = vp[HDIM];     dst[2] = vp[2*HDIM]; dst[3] = vp[3*HDIM]; \
    dst[4] = vp[4*HDIM];   dst[5] = vp[5*HDIM];   dst[6] = vp[6*HDIM]; dst[7] = vp[7*HDIM]; }
#define PVSTEP(kc, vsrc) { \
    bf16x8_t vbf; PKV(vsrc, vbf); \
    const int ke = kbase + (kc) * 32 + kg * 8; \
    const bf16x8_t pa0 = *(const bf16x8_t*)pelemc(Plds, col,      ke); \
    const bf16x8_t pa1 = *(const bf16x8_t*)pelemc(Plds, 16 + col, ke); \
    cacc0 = __builtin_amdgcn_mfma_f32_16x16x32_bf16(pa0, vbf, cacc0, 0,0,0); \
    cacc1 = __builtin_amdgcn_mfma_f32_16x16x32_bf16(pa1, vbf, cacc1, 0,0,0); }
        LOADV(0, vr0); LOADV(1, vr1);
        #pragma unroll 1
        for (int kc = 0; kc < 30; kc += 2) {
            PVSTEP(kc,     vr0); LOADV(kc + 2, vr0);
            PVSTEP(kc + 1, vr1); LOADV(kc + 3, vr1);
        }
        PVSTEP(30, vr0);
        PVSTEP(31, vr1);
#undef LOADV
#undef PVSTEP
    }

    // ---- Phase 2b (ROLLED): attn store stream
    {
        const int srow = w * 4 + kg;
        const float my_rinv = rinv_s[srow];
        float* abp = attn_out + ((size_t)b * S_LEN + q0 + srow) * S_LEN + col * 4;
        #pragma unroll 1
        for (int sec = 0; sec < 32; ++sec) {
            const s16x4_t pv = *(const s16x4_t*)pelemc(Plds, srow, sec * 64 + col * 4);
            f32x4_t o;
            o[0] = bf2f(pv[0]) * my_rinv; o[1] = bf2f(pv[1]) * my_rinv;
            o[2] = bf2f(pv[2]) * my_rinv; o[3] = bf2f(pv[3]) * my_rinv;
            *(f32x4_t*)(abp + sec * 64) = o;
        }
    }

    // ---- ctx: reduce k-halves, normalize, store
    if (w >= 4) {
        #pragma unroll
        for (int r = 0; r < 4; ++r) {
            Pvp[w - 4][kg * 4 + r][col]      = cacc0[r];
            Pvp[w - 4][16 + kg * 4 + r][col] = cacc1[r];
        }
    }
    __syncthreads();
    if (w < 4) {
        #pragma unroll
        for (int r = 0; r < 4; ++r) {
            const int row0 = kg * 4 + r;
            const int row1 = 16 + kg * 4 + r;
            OUT[((size_t)b * S_LEN + q0 + row0) * HDIM + hb + col]
                = (cacc0[r] + Pvp[w][row0][col]) * rinv_s[row0];
            OUT[((size_t)b * S_LEN + q0 + row1) * HDIM + hb + col]
                = (cacc1[r] + Pvp[w][row1][col]) * rinv_s[row1];
        }
    }
}

extern "C" void kernel_launch(void* const* d_in, const int* in_sizes, int n_in,
                              void* d_out, int out_size, void* d_ws, size_t ws_size,
                              hipStream_t stream)
{
    const float* q = (const float*)d_in[0];
    const float* k = (const float*)d_in[1];
    const float* v = (const float*)d_in[2];
    const unsigned char* mask = (const unsigned char*)d_in[3];
    int* mflags = (int*)d_ws;
    float* out = (float*)d_out;
    detect_mask<<<dim3(1), dim3(256), 0, stream>>>(mask, mflags);
    sdpa_one<<<dim3(2048), dim3(NTHREADS), 0, stream>>>(q, k, v, mask, mflags, out);
}

// Round 17
// 451.682 us; speedup vs baseline: 1.0309x; 1.0309x over previous
//
#include <hip/hip_runtime.h>
#include <hip/hip_bf16.h>

typedef __bf16    bf16x8_t __attribute__((ext_vector_type(8)));
typedef float     f32x4_t  __attribute__((ext_vector_type(4)));
typedef short     s16x4_t  __attribute__((ext_vector_type(4)));
typedef short     s16x8_t  __attribute__((ext_vector_type(8)));
typedef unsigned  u32x4_t  __attribute__((ext_vector_type(4)));

#define S_LEN 2048
#define HDIM  64
#define BQ    32
#define NTHREADS 1024
#define PSTR_B 4112       // P row byte stride; %128B=16 -> rows shift 4 banks
#define BMSTR 264

__device__ __forceinline__ short f2bf(float f) {
    return __builtin_bit_cast(short, (__bf16)f);
}
__device__ __forceinline__ float bf2f(short s) {
    return __builtin_bit_cast(float, ((unsigned)(unsigned short)s) << 16);
}
__device__ __forceinline__ short* pelem(short* P, int row, int e) {
    return (short*)((char*)P + (unsigned)row * PSTR_B + (unsigned)e * 2u);
}
__device__ __forceinline__ const short* pelemc(const short* P, int row, int e) {
    return pelem(const_cast<short*>(P), row, e);
}
__device__ __forceinline__ unsigned nzmask16(u32x4_t w) {
    unsigned n = 0;
    #pragma unroll
    for (int i = 0; i < 4; ++i) {
        const unsigned x = w[i];
        const unsigned t = (x & 0x7F7F7F7Fu) + 0x7F7F7F7Fu;
        const unsigned z = ((t | x) & 0x80808080u) >> 7;
        n |= ((z * 0x10204081u) >> 28) << (4 * i);
    }
    return n;
}
__device__ __forceinline__ unsigned nzmask4w(u32x4_t w) {
    return (w[0] ? 1u : 0u) | (w[1] ? 2u : 0u) | (w[2] ? 4u : 0u) | (w[3] ? 8u : 0u);
}

#define PK8(lo, hi, out8) { s16x8_t _t; \
    _t[0]=f2bf((lo)[0]); _t[1]=f2bf((lo)[1]); _t[2]=f2bf((lo)[2]); _t[3]=f2bf((lo)[3]); \
    _t[4]=f2bf((hi)[0]); _t[5]=f2bf((hi)[1]); _t[6]=f2bf((hi)[2]); _t[7]=f2bf((hi)[3]); \
    (out8) = __builtin_bit_cast(bf16x8_t, _t); }
#define PKV(src, dst) { s16x8_t _t; \
    _t[0]=f2bf((src)[0]); _t[1]=f2bf((src)[1]); _t[2]=f2bf((src)[2]); _t[3]=f2bf((src)[3]); \
    _t[4]=f2bf((src)[4]); _t[5]=f2bf((src)[5]); _t[6]=f2bf((src)[6]); _t[7]=f2bf((src)[7]); \
    (dst) = __builtin_bit_cast(bf16x8_t, _t); }

__global__ void detect_mask(const unsigned char* __restrict__ M, int* __restrict__ flags) {
    __shared__ int cnt[4];
    if (threadIdx.x < 4) cnt[threadIdx.x] = 0;
    __syncthreads();
    int local[4] = {0, 0, 0, 0};
    for (int i = threadIdx.x; i < 16384; i += 256)
        if (M[i]) local[i & 3]++;
    #pragma unroll
    for (int c = 0; c < 4; ++c)
        if (local[c]) atomicAdd(&cnt[c], local[c]);
    __syncthreads();
    if (threadIdx.x == 0) {
        int stride;
        if (cnt[1] == 0 && cnt[2] == 0 && cnt[3] == 0)      stride = 4;  // int32
        else if (cnt[0] == 0 && cnt[1] == 0)                stride = 4;  // float32
        else                                                stride = 1;  // bool/int8
        flags[0] = stride;
    }
}

// r16 retry (fixed): 1024 threads = 4 waves/SIMD, registers unconstrained.
// FIX vs r16: PV partials now go into a zeroed LDS accumulator Pvx[BQ][64]
// via atomicAdd (r16's Pvp[(w>>2)-1] dropped the colgroup dim -> waves with
// same k-quarter, different colgroups collided -> absmax 0.61).
__global__ __launch_bounds__(NTHREADS, 1)
void sdpa_one(const float* __restrict__ Q, const float* __restrict__ K,
              const float* __restrict__ V, const unsigned char* __restrict__ M,
              const int* __restrict__ MF, float* __restrict__ OUT)
{
    __shared__ short Plds[BQ * (PSTR_B / 2)];      // 131584 B unnormalized exp bf16
    __shared__ unsigned char Bm[BQ * BMSTR];       // 8448 B mask bits
    __shared__ float Pvx[BQ][HDIM];                // 8192 B PV accumulator (atomicAdd)
    __shared__ float rowsum[BQ];
    __shared__ float rinv_s[BQ];

    const int tid  = threadIdx.x;
    const int w    = tid >> 6;        // 0..15
    const int lane = tid & 63;
    const int col  = lane & 15;
    const int kg   = lane >> 4;
    const int mstride = MF[0];

    // 2048 blocks = 8 xcd * 256 slots (bijective)
    const int id   = blockIdx.x;
    const int slot = id >> 3;
    const int b    = ((slot >> 6) << 3) | (id & 7);
    const int q0   = (slot & 63) * BQ;

    float* attn_out = OUT + (size_t)32 * S_LEN * HDIM;

    if (tid < BQ) rowsum[tid] = 0.f;
    {   // zero the PV accumulator (2 floats/thread)
        float* pz = &Pvx[0][0];
        pz[tid] = 0.f;
        pz[tid + 1024] = 0.f;
    }

    {   // ---- mask tile -> 1-bit/elem LDS bitmask (1024 threads, 64 elems each)
        const int row  = tid >> 5;            // 0..31
        const int segE = (tid & 31) * 64;
        unsigned long long bits = 0ull;
        if (mstride == 1) {
            const unsigned char* mp = M + (size_t)b * S_LEN * S_LEN
                                        + (size_t)(q0 + row) * S_LEN + segE;
            #pragma unroll
            for (int j = 0; j < 4; ++j)
                bits |= (unsigned long long)nzmask16(*(const u32x4_t*)(mp + j * 16))
                        << (16 * j);
        } else {
            const unsigned* mp = (const unsigned*)M + (size_t)b * S_LEN * S_LEN
                                   + (size_t)(q0 + row) * S_LEN + segE;
            #pragma unroll
            for (int j = 0; j < 16; ++j)
                bits |= (unsigned long long)nzmask4w(*(const u32x4_t*)(mp + j * 4))
                        << (4 * j);
        }
        *(unsigned long long*)&Bm[row * BMSTR + (segE >> 3)] = bits;
    }

    // Q fragments (MFMA B-operand after swap)
    bf16x8_t af[2][2];
    #pragma unroll
    for (int m = 0; m < 2; ++m)
        #pragma unroll
        for (int kk = 0; kk < 2; ++kk) {
            const float* qp = Q + ((size_t)b * S_LEN + q0 + m * 16 + col) * HDIM + kk * 32 + kg * 8;
            const f32x4_t qa = *(const f32x4_t*)qp;
            const f32x4_t qb = *(const f32x4_t*)(qp + 4);
            PK8(qa, qb, af[m][kk]);
        }
    __syncthreads();

    // ---- Phase 1: swapped QK^T, 16 waves x 8 STEPs (128 k-cols each).
    // D = mfma(K_frag, Q_frag): lane(col,kg) reg r -> P[m*16+col][n0+kg*4+r].
    float rs0 = 0.f, rs1 = 0.f;
    {
        const float* Kb = K + (size_t)b * S_LEN * HDIM;
        f32x4_t A0,B0,C0,D0, A1,B1,C1,D1;
#define LDK(f, AX,BX,CX,DX) { \
    const float* kp = Kb + (size_t)(w * 128 + (f) * 16 + col) * HDIM + kg * 8; \
    AX = *(const f32x4_t*)kp;        BX = *(const f32x4_t*)(kp + 4); \
    CX = *(const f32x4_t*)(kp + 32); DX = *(const f32x4_t*)(kp + 36); }
#define STEP(f, AX,BX,CX,DX, PF, fp) { \
    bf16x8_t kb0, kb1; PK8(AX, BX, kb0); PK8(CX, DX, kb1); \
    if (PF) LDK(fp, AX,BX,CX,DX); \
    f32x4_t acc0 = {0.f,0.f,0.f,0.f}, acc1 = {0.f,0.f,0.f,0.f}; \
    acc0 = __builtin_amdgcn_mfma_f32_16x16x32_bf16(kb0, af[0][0], acc0, 0,0,0); \
    acc0 = __builtin_amdgcn_mfma_f32_16x16x32_bf16(kb1, af[0][1], acc0, 0,0,0); \
    acc1 = __builtin_amdgcn_mfma_f32_16x16x32_bf16(kb0, af[1][0], acc1, 0,0,0); \
    acc1 = __builtin_amdgcn_mfma_f32_16x16x32_bf16(kb1, af[1][1], acc1, 0,0,0); \
    const int c0 = w * 128 + (f) * 16 + kg * 4; \
    const int sh = c0 & 7; \
    { const unsigned bb = Bm[col * BMSTR + (c0 >> 3)]; \
      float p0 = ((bb >> (sh    )) & 1u) ? 0.f : __expf(acc0[0] * 0.125f); \
      float p1 = ((bb >> (sh + 1)) & 1u) ? 0.f : __expf(acc0[1] * 0.125f); \
      float p2 = ((bb >> (sh + 2)) & 1u) ? 0.f : __expf(acc0[2] * 0.125f); \
      float p3 = ((bb >> (sh + 3)) & 1u) ? 0.f : __expf(acc0[3] * 0.125f); \
      rs0 += (p0 + p1) + (p2 + p3); \
      s16x4_t pk; pk[0]=f2bf(p0); pk[1]=f2bf(p1); pk[2]=f2bf(p2); pk[3]=f2bf(p3); \
      *(s16x4_t*)pelem(Plds, col, c0) = pk; } \
    { const unsigned bb = Bm[(16 + col) * BMSTR + (c0 >> 3)]; \
      float p0 = ((bb >> (sh    )) & 1u) ? 0.f : __expf(acc1[0] * 0.125f); \
      float p1 = ((bb >> (sh + 1)) & 1u) ? 0.f : __expf(acc1[1] * 0.125f); \
      float p2 = ((bb >> (sh + 2)) & 1u) ? 0.f : __expf(acc1[2] * 0.125f); \
      float p3 = ((bb >> (sh + 3)) & 1u) ? 0.f : __expf(acc1[3] * 0.125f); \
      rs1 += (p0 + p1) + (p2 + p3); \
      s16x4_t pk; pk[0]=f2bf(p0); pk[1]=f2bf(p1); pk[2]=f2bf(p2); pk[3]=f2bf(p3); \
      *(s16x4_t*)pelem(Plds, 16 + col, c0) = pk; } }
        LDK(0, A0,B0,C0,D0);
        LDK(1, A1,B1,C1,D1);
        #pragma unroll
        for (int ff = 0; ff < 8; ff += 2) {
            STEP(ff,     A0,B0,C0,D0, (ff + 2 < 8), ff + 2);
            STEP(ff + 1, A1,B1,C1,D1, (ff + 3 < 8), ff + 3);
        }
#undef LDK
#undef STEP
    }
    {
        float s0 = rs0, s1 = rs1;
        s0 += __shfl_xor(s0, 16); s0 += __shfl_xor(s0, 32);
        s1 += __shfl_xor(s1, 16); s1 += __shfl_xor(s1, 32);
        if (lane < 16) {
            atomicAdd(&rowsum[col], s0);
            atomicAdd(&rowsum[16 + col], s1);
        }
    }
    __syncthreads();
    if (tid < BQ) rinv_s[tid] = 1.0f / rowsum[tid];
    __syncthreads();

    // ---- Phase 2a: pure PV, k in QUARTERS across 16 waves.
    // wave = (kquarter<<2) | colgroup; each wave: 512 k x 16 ctx cols.
    const int hb    = (w & 3) * 16;
    const int kbase = (w >> 2) * 512;
    const float* Vb = V + (size_t)b * S_LEN * HDIM;

    f32x4_t cacc0 = {0.f,0.f,0.f,0.f}, cacc1 = {0.f,0.f,0.f,0.f};
    {
        float vr0[8], vr1[8];
#define LOADV(kc, dst) { \
    const float* vp = Vb + (size_t)(kbase + (kc) * 32 + kg * 8) * HDIM + hb + col; \
    dst[0] = vp[0];        dst[1] = vp[HDIM];     dst[2] = vp[2*HDIM]; dst[3] = vp[3*HDIM]; \
    dst[4] = vp[4*HDIM];   dst[5] = vp[5*HDIM];   dst[6] = vp[6*HDIM]; dst[7] = vp[7*HDIM]; }
#define PVSTEP(kc, vsrc) { \
    bf16x8_t vbf; PKV(vsrc, vbf); \
    const int ke = kbase + (kc) * 32 + kg * 8; \
    const bf16x8_t pa0 = *(const bf16x8_t*)pelemc(Plds, col,      ke); \
    const bf16x8_t pa1 = *(const bf16x8_t*)pelemc(Plds, 16 + col, ke); \
    cacc0 = __builtin_amdgcn_mfma_f32_16x16x32_bf16(pa0, vbf, cacc0, 0,0,0); \
    cacc1 = __builtin_amdgcn_mfma_f32_16x16x32_bf16(pa1, vbf, cacc1, 0,0,0); }
        LOADV(0, vr0); LOADV(1, vr1);
        #pragma unroll
        for (int kc = 0; kc < 14; kc += 2) {
            PVSTEP(kc,     vr0); LOADV(kc + 2, vr0);
            PVSTEP(kc + 1, vr1); LOADV(kc + 3, vr1);
        }
        PVSTEP(14, vr0);
        PVSTEP(15, vr1);
#undef LOADV
#undef PVSTEP
    }
    // accumulate PV partials (4 adds per (row,col) across k-quarters)
    #pragma unroll
    for (int r = 0; r < 4; ++r) {
        atomicAdd(&Pvx[kg * 4 + r][hb + col],      cacc0[r]);
        atomicAdd(&Pvx[16 + kg * 4 + r][hb + col], cacc1[r]);
    }

    // ---- Phase 2b: attn store stream — 16 waves x 2 rows, 512B/instr
    {
        const int srow = w * 2 + (lane >> 5);
        const int lc   = lane & 31;
        const float my_rinv = rinv_s[srow];
        float* abp = attn_out + ((size_t)b * S_LEN + q0 + srow) * S_LEN + lc * 4;
        #pragma unroll 4
        for (int sec = 0; sec < 16; ++sec) {
            const s16x4_t pv = *(const s16x4_t*)pelemc(Plds, srow, sec * 128 + lc * 4);
            f32x4_t o;
            o[0] = bf2f(pv[0]) * my_rinv; o[1] = bf2f(pv[1]) * my_rinv;
            o[2] = bf2f(pv[2]) * my_rinv; o[3] = bf2f(pv[3]) * my_rinv;
            *(f32x4_t*)(abp + sec * 128) = o;
        }
    }

    // ---- ctx: normalize accumulated PV, flat store (2 floats/thread)
    __syncthreads();
    {
        const int row = tid >> 5;             // 0..31
        const int c0  = (tid & 31) * 2;       // 0..62
        const float ri = rinv_s[row];
        float2 o;
        o.x = Pvx[row][c0]     * ri;
        o.y = Pvx[row][c0 + 1] * ri;
        *(float2*)(OUT + ((size_t)b * S_LEN + q0 + row) * HDIM + c0) = o;
    }
}

extern "C" void kernel_launch(void* const* d_in, const int* in_sizes, int n_in,
                              void* d_out, int out_size, void* d_ws, size_t ws_size,
                              hipStream_t stream)
{
    const float* q = (const float*)d_in[0];
    const float* k = (const float*)d_in[1];
    const float* v = (const float*)d_in[2];
    const unsigned char* mask = (const unsigned char*)d_in[3];
    int* mflags = (int*)d_ws;
    float* out = (float*)d_out;
    detect_mask<<<dim3(1), dim3(256), 0, stream>>>(mask, mflags);
    sdpa_one<<<dim3(2048), dim3(NTHREADS), 0, stream>>>(q, k, v, mask, mflags, out);
}